// Round 1
// baseline (722.254 us; speedup 1.0000x reference)
//
#include <hip/hip_runtime.h>

#define N_NODES 50000
#define N_EDGES 800000
#define N_GRAPHS 64
#define D_IN 128
#define D_HID 64
#define D_OUT 32

// ---------------------------------------------------------------- degree ----
__global__ __launch_bounds__(256) void k_deg_init(float* __restrict__ deg) {
    int v = blockIdx.x * 256 + threadIdx.x;
    if (v < N_NODES) deg[v] = 1.0f;   // self-loop contributes 1
}

__global__ __launch_bounds__(256) void k_deg_edges(const int* __restrict__ dst,
                                                   float* __restrict__ deg) {
    int e = blockIdx.x * 256 + threadIdx.x;
    if (e < N_EDGES) atomicAdd(&deg[dst[e]], 1.0f);
}

__global__ __launch_bounds__(256) void k_dinv(const float* __restrict__ deg,
                                              float* __restrict__ dinv) {
    int v = blockIdx.x * 256 + threadIdx.x;
    if (v < N_NODES) dinv[v] = rsqrtf(deg[v]);   // deg >= 1 always
}

// ------------------------------------------------- conv1 matmul (fused) -----
// hs1[u] = ((x[u]/max(rowsum,1)) @ W1) * dinv[u]; agg1 seeded with self-loop.
__global__ __launch_bounds__(256) void k_mm1(const float* __restrict__ x,
                                             const float* __restrict__ W1,
                                             const float* __restrict__ dinv,
                                             float* __restrict__ hs1,
                                             float* __restrict__ agg1) {
    __shared__ float w1s[D_IN * D_HID];      // 32 KiB
    __shared__ float xr[4][D_IN + 4];        // pad: nd-groups land on distinct banks
    __shared__ float sinv[4];
    const int tid = threadIdx.x;

    for (int i = tid; i < D_IN * D_HID; i += 256) w1s[i] = W1[i];

    const int base = blockIdx.x * 4;
    for (int i = tid; i < 4 * D_IN; i += 256) {
        int nd = i >> 7, k = i & 127;
        int node = base + nd;
        xr[nd][k] = (node < N_NODES) ? x[(size_t)node * D_IN + k] : 0.0f;
    }
    __syncthreads();

    // one wave (64 lanes) per node: row-sum reduce
    const int nd = tid >> 6, lane = tid & 63;
    float p = xr[nd][lane] + xr[nd][lane + 64];
    for (int off = 32; off > 0; off >>= 1) p += __shfl_down(p, off, 64);
    if (lane == 0) sinv[nd] = 1.0f / fmaxf(p, 1.0f);
    __syncthreads();

    const int c = tid & 63;
    const int node = base + nd;
    if (node < N_NODES) {
        float acc = 0.0f;
        #pragma unroll 8
        for (int k = 0; k < D_IN; ++k) acc += xr[nd][k] * w1s[k * D_HID + c];
        float hv = acc * sinv[nd] * dinv[node];
        hs1[(size_t)node * D_HID + c] = hv;
        agg1[(size_t)node * D_HID + c] = hv;   // self-loop seed
    }
}

// ------------------------------------------------------------- scatter1 -----
// one wave per edge; lane = channel (64)
__global__ __launch_bounds__(256) void k_scatter1(const int* __restrict__ src,
                                                  const int* __restrict__ dst,
                                                  const float* __restrict__ hs1,
                                                  float* __restrict__ agg1) {
    int e = blockIdx.x * 4 + (threadIdx.x >> 6);
    int lane = threadIdx.x & 63;
    if (e < N_EDGES) {
        int s = src[e], d = dst[e];
        atomicAdd(&agg1[(size_t)d * D_HID + lane], hs1[(size_t)s * D_HID + lane]);
    }
}

// ------------------------------- conv1 epilogue + conv2 matmul (fused) ------
// h1 = relu(dinv*agg1 + b1); hs2 = (h1 @ W2) * dinv; agg2 seeded.
__global__ __launch_bounds__(256) void k_mm2(const float* __restrict__ agg1,
                                             const float* __restrict__ W2,
                                             const float* __restrict__ b1,
                                             const float* __restrict__ dinv,
                                             float* __restrict__ hs2,
                                             float* __restrict__ agg2) {
    __shared__ float w2s[D_HID * D_OUT];     // 8 KiB
    __shared__ float h1s[8][D_HID];          // 2-way LDS aliasing only (free)
    const int tid = threadIdx.x;

    for (int i = tid; i < D_HID * D_OUT; i += 256) w2s[i] = W2[i];

    const int base = blockIdx.x * 8;
    for (int i = tid; i < 8 * D_HID; i += 256) {
        int nd = i >> 6, k = i & 63;
        int node = base + nd;
        h1s[nd][k] = (node < N_NODES)
                   ? fmaxf(dinv[node] * agg1[(size_t)node * D_HID + k] + b1[k], 0.0f)
                   : 0.0f;
    }
    __syncthreads();

    const int nd = tid >> 5, c = tid & 31;
    const int node = base + nd;
    if (node < N_NODES) {
        float acc = 0.0f;
        #pragma unroll 8
        for (int k = 0; k < D_HID; ++k) acc += h1s[nd][k] * w2s[k * D_OUT + c];
        float hv = acc * dinv[node];
        hs2[(size_t)node * D_OUT + c] = hv;
        agg2[(size_t)node * D_OUT + c] = hv;   // self-loop seed
    }
}

// ------------------------------------------------------------- scatter2 -----
__global__ __launch_bounds__(256) void k_scatter2(const int* __restrict__ src,
                                                  const int* __restrict__ dst,
                                                  const float* __restrict__ hs2,
                                                  float* __restrict__ agg2) {
    int e = blockIdx.x * 8 + (threadIdx.x >> 5);
    int c = threadIdx.x & 31;
    if (e < N_EDGES) {
        int s = src[e], d = dst[e];
        atomicAdd(&agg2[(size_t)d * D_OUT + c], hs2[(size_t)s * D_OUT + c]);
    }
}

// ------------------------------------------- conv2 epilogue + mean pool -----
__global__ __launch_bounds__(256) void k_pool(const float* __restrict__ agg2,
                                              const float* __restrict__ b2,
                                              const float* __restrict__ dinv,
                                              const int* __restrict__ batch,
                                              float* __restrict__ psum,
                                              float* __restrict__ pcnt) {
    const int nd = threadIdx.x >> 5, c = threadIdx.x & 31;
    const int node = blockIdx.x * 8 + nd;
    if (node < N_NODES) {
        float hv = fmaxf(dinv[node] * agg2[(size_t)node * D_OUT + c] + b2[c], 0.0f);
        int g = batch[node];
        atomicAdd(&psum[g * D_OUT + c], hv);
        if (c == 0) atomicAdd(&pcnt[g], 1.0f);
    }
}

__global__ __launch_bounds__(256) void k_final(const float* __restrict__ psum,
                                               const float* __restrict__ pcnt,
                                               float* __restrict__ out) {
    int i = blockIdx.x * 256 + threadIdx.x;
    if (i < N_GRAPHS * D_OUT) {
        int g = i / D_OUT;
        out[i] = psum[i] / fmaxf(pcnt[g], 1.0f);
    }
}

// ---------------------------------------------------------------------------
extern "C" void kernel_launch(void* const* d_in, const int* in_sizes, int n_in,
                              void* d_out, int out_size, void* d_ws, size_t ws_size,
                              hipStream_t stream) {
    const float* x     = (const float*)d_in[0];
    const int*   edge  = (const int*)d_in[1];   // [2, E] int
    const int*   batch = (const int*)d_in[2];   // [N] int (sorted)
    const float* W1    = (const float*)d_in[3];
    const float* b1    = (const float*)d_in[4];
    const float* W2    = (const float*)d_in[5];
    const float* b2    = (const float*)d_in[6];
    float* out = (float*)d_out;

    const int* src = edge;             // row 0
    const int* dst = edge + N_EDGES;   // row 1

    float* ws   = (float*)d_ws;
    float* deg  = ws;                                   // N
    float* dinv = deg  + N_NODES;                       // N
    float* hs1  = dinv + N_NODES;                       // N*64
    float* agg1 = hs1  + (size_t)N_NODES * D_HID;       // N*64
    float* hs2  = agg1 + (size_t)N_NODES * D_HID;       // N*32
    float* agg2 = hs2  + (size_t)N_NODES * D_OUT;       // N*32
    float* psum = agg2 + (size_t)N_NODES * D_OUT;       // G*32
    float* pcnt = psum + N_GRAPHS * D_OUT;              // G

    hipMemsetAsync(psum, 0, (N_GRAPHS * D_OUT + N_GRAPHS) * sizeof(float), stream);

    k_deg_init <<<(N_NODES + 255) / 256, 256, 0, stream>>>(deg);
    k_deg_edges<<<(N_EDGES + 255) / 256, 256, 0, stream>>>(dst, deg);
    k_dinv     <<<(N_NODES + 255) / 256, 256, 0, stream>>>(deg, dinv);
    k_mm1      <<<(N_NODES + 3) / 4,     256, 0, stream>>>(x, W1, dinv, hs1, agg1);
    k_scatter1 <<<(N_EDGES + 3) / 4,     256, 0, stream>>>(src, dst, hs1, agg1);
    k_mm2      <<<(N_NODES + 7) / 8,     256, 0, stream>>>(agg1, W2, b1, dinv, hs2, agg2);
    k_scatter2 <<<(N_EDGES + 7) / 8,     256, 0, stream>>>(src, dst, hs2, agg2);
    k_pool     <<<(N_NODES + 7) / 8,     256, 0, stream>>>(agg2, b2, dinv, batch, psum, pcnt);
    k_final    <<<(N_GRAPHS * D_OUT + 255) / 256, 256, 0, stream>>>(psum, pcnt, out);
}

// Round 2
// 412.668 us; speedup vs baseline: 1.7502x; 1.7502x over previous
//
#include <hip/hip_runtime.h>

#define N_NODES 50000
#define N_EDGES 800000
#define N_GRAPHS 64
#define D_IN 128
#define D_HID 64
#define D_OUT 32
#define POOL_TILE 512

// ---------------------------------------------------------------- degree ----
__global__ __launch_bounds__(256) void k_deg_init(float* __restrict__ deg) {
    int v = blockIdx.x * 256 + threadIdx.x;
    if (v < N_NODES) deg[v] = 1.0f;   // self-loop contributes 1
}

__global__ __launch_bounds__(256) void k_deg_edges(const int* __restrict__ dst,
                                                   float* __restrict__ deg) {
    int e = blockIdx.x * 256 + threadIdx.x;
    if (e < N_EDGES) atomicAdd(&deg[dst[e]], 1.0f);
}

__global__ __launch_bounds__(256) void k_dinv(const float* __restrict__ deg,
                                              float* __restrict__ dinv) {
    int v = blockIdx.x * 256 + threadIdx.x;
    if (v < N_NODES) dinv[v] = rsqrtf(deg[v]);   // deg >= 1 always
}

// ------------------------------------------------- conv1 matmul (fused) -----
// hs1[u] = ((x[u]/max(rowsum,1)) @ W1) * dinv[u]; agg1 seeded with self-loop.
__global__ __launch_bounds__(256) void k_mm1(const float* __restrict__ x,
                                             const float* __restrict__ W1,
                                             const float* __restrict__ dinv,
                                             float* __restrict__ hs1,
                                             float* __restrict__ agg1) {
    __shared__ float w1s[D_IN * D_HID];      // 32 KiB
    __shared__ float xr[4][D_IN + 4];        // pad: nd-groups land on distinct banks
    __shared__ float sinv[4];
    const int tid = threadIdx.x;

    for (int i = tid; i < D_IN * D_HID; i += 256) w1s[i] = W1[i];

    const int base = blockIdx.x * 4;
    for (int i = tid; i < 4 * D_IN; i += 256) {
        int nd = i >> 7, k = i & 127;
        int node = base + nd;
        xr[nd][k] = (node < N_NODES) ? x[(size_t)node * D_IN + k] : 0.0f;
    }
    __syncthreads();

    // one wave (64 lanes) per node: row-sum reduce
    const int nd = tid >> 6, lane = tid & 63;
    float p = xr[nd][lane] + xr[nd][lane + 64];
    for (int off = 32; off > 0; off >>= 1) p += __shfl_down(p, off, 64);
    if (lane == 0) sinv[nd] = 1.0f / fmaxf(p, 1.0f);
    __syncthreads();

    const int c = tid & 63;
    const int node = base + nd;
    if (node < N_NODES) {
        float acc = 0.0f;
        #pragma unroll 8
        for (int k = 0; k < D_IN; ++k) acc += xr[nd][k] * w1s[k * D_HID + c];
        float hv = acc * sinv[nd] * dinv[node];
        hs1[(size_t)node * D_HID + c] = hv;
        agg1[(size_t)node * D_HID + c] = hv;   // self-loop seed
    }
}

// ------------------------------------------------------------- scatter1 -----
// one wave per edge; lane = channel (64)
__global__ __launch_bounds__(256) void k_scatter1(const int* __restrict__ src,
                                                  const int* __restrict__ dst,
                                                  const float* __restrict__ hs1,
                                                  float* __restrict__ agg1) {
    int e = blockIdx.x * 4 + (threadIdx.x >> 6);
    int lane = threadIdx.x & 63;
    if (e < N_EDGES) {
        int s = src[e], d = dst[e];
        atomicAdd(&agg1[(size_t)d * D_HID + lane], hs1[(size_t)s * D_HID + lane]);
    }
}

// ------------------------------- conv1 epilogue + conv2 matmul (fused) ------
// h1 = relu(dinv*agg1 + b1); hs2 = (h1 @ W2) * dinv; agg2 seeded.
__global__ __launch_bounds__(256) void k_mm2(const float* __restrict__ agg1,
                                             const float* __restrict__ W2,
                                             const float* __restrict__ b1,
                                             const float* __restrict__ dinv,
                                             float* __restrict__ hs2,
                                             float* __restrict__ agg2) {
    __shared__ float w2s[D_HID * D_OUT];     // 8 KiB
    __shared__ float h1s[8][D_HID];          // 2-way LDS aliasing only (free)
    const int tid = threadIdx.x;

    for (int i = tid; i < D_HID * D_OUT; i += 256) w2s[i] = W2[i];

    const int base = blockIdx.x * 8;
    for (int i = tid; i < 8 * D_HID; i += 256) {
        int nd = i >> 6, k = i & 63;
        int node = base + nd;
        h1s[nd][k] = (node < N_NODES)
                   ? fmaxf(dinv[node] * agg1[(size_t)node * D_HID + k] + b1[k], 0.0f)
                   : 0.0f;
    }
    __syncthreads();

    const int nd = tid >> 5, c = tid & 31;
    const int node = base + nd;
    if (node < N_NODES) {
        float acc = 0.0f;
        #pragma unroll 8
        for (int k = 0; k < D_HID; ++k) acc += h1s[nd][k] * w2s[k * D_OUT + c];
        float hv = acc * dinv[node];
        hs2[(size_t)node * D_OUT + c] = hv;
        agg2[(size_t)node * D_OUT + c] = hv;   // self-loop seed
    }
}

// ------------------------------------------------------------- scatter2 -----
__global__ __launch_bounds__(256) void k_scatter2(const int* __restrict__ src,
                                                  const int* __restrict__ dst,
                                                  const float* __restrict__ hs2,
                                                  float* __restrict__ agg2) {
    int e = blockIdx.x * 8 + (threadIdx.x >> 5);
    int c = threadIdx.x & 31;
    if (e < N_EDGES) {
        int s = src[e], d = dst[e];
        atomicAdd(&agg2[(size_t)d * D_OUT + c], hs2[(size_t)s * D_OUT + c]);
    }
}

// ------------------------------------------- conv2 epilogue + mean pool -----
// batch is SORTED: per-thread register segment-accumulate, flush on graph
// change. Atomics: ~256 * nblocks * ~1.5 instead of N_NODES*32.
__global__ __launch_bounds__(256) void k_pool(const float* __restrict__ agg2,
                                              const float* __restrict__ b2,
                                              const float* __restrict__ dinv,
                                              const int* __restrict__ batch,
                                              float* __restrict__ psum) {
    const int c = threadIdx.x & 31;          // channel
    const int slot = threadIdx.x >> 5;       // 8 node slots per block
    const int base = blockIdx.x * POOL_TILE;
    const float bc = b2[c];

    float acc = 0.0f;
    int curg = -1;
    for (int j = slot; j < POOL_TILE; j += 8) {
        int node = base + j;
        if (node >= N_NODES) break;
        float hv = fmaxf(dinv[node] * agg2[(size_t)node * D_OUT + c] + bc, 0.0f);
        int g = batch[node];
        if (g != curg) {
            if (curg >= 0) atomicAdd(&psum[curg * D_OUT + c], acc);
            curg = g;
            acc = 0.0f;
        }
        acc += hv;
    }
    if (curg >= 0) atomicAdd(&psum[curg * D_OUT + c], acc);
}

// counts via binary search over sorted batch (no pcnt atomics at all)
__global__ __launch_bounds__(256) void k_final(const float* __restrict__ psum,
                                               const int* __restrict__ batch,
                                               float* __restrict__ out) {
    int i = blockIdx.x * 256 + threadIdx.x;
    if (i < N_GRAPHS * D_OUT) {
        int g = i >> 5;   // D_OUT == 32
        int lo = 0, hi = N_NODES;
        while (lo < hi) { int m = (lo + hi) >> 1; if (batch[m] < g) lo = m + 1; else hi = m; }
        int lb = lo;
        lo = 0; hi = N_NODES;
        while (lo < hi) { int m = (lo + hi) >> 1; if (batch[m] <= g) lo = m + 1; else hi = m; }
        float cnt = (float)(lo - lb);
        out[i] = psum[i] / fmaxf(cnt, 1.0f);
    }
}

// ---------------------------------------------------------------------------
extern "C" void kernel_launch(void* const* d_in, const int* in_sizes, int n_in,
                              void* d_out, int out_size, void* d_ws, size_t ws_size,
                              hipStream_t stream) {
    const float* x     = (const float*)d_in[0];
    const int*   edge  = (const int*)d_in[1];   // [2, E] int
    const int*   batch = (const int*)d_in[2];   // [N] int (sorted)
    const float* W1    = (const float*)d_in[3];
    const float* b1    = (const float*)d_in[4];
    const float* W2    = (const float*)d_in[5];
    const float* b2    = (const float*)d_in[6];
    float* out = (float*)d_out;

    const int* src = edge;             // row 0
    const int* dst = edge + N_EDGES;   // row 1

    float* ws   = (float*)d_ws;
    float* deg  = ws;                                   // N
    float* dinv = deg  + N_NODES;                       // N
    float* hs1  = dinv + N_NODES;                       // N*64
    float* agg1 = hs1  + (size_t)N_NODES * D_HID;       // N*64
    float* hs2  = agg1 + (size_t)N_NODES * D_HID;       // N*32
    float* agg2 = hs2  + (size_t)N_NODES * D_OUT;       // N*32
    float* psum = agg2 + (size_t)N_NODES * D_OUT;       // G*32

    hipMemsetAsync(psum, 0, N_GRAPHS * D_OUT * sizeof(float), stream);

    k_deg_init <<<(N_NODES + 255) / 256, 256, 0, stream>>>(deg);
    k_deg_edges<<<(N_EDGES + 255) / 256, 256, 0, stream>>>(dst, deg);
    k_dinv     <<<(N_NODES + 255) / 256, 256, 0, stream>>>(deg, dinv);
    k_mm1      <<<(N_NODES + 3) / 4,     256, 0, stream>>>(x, W1, dinv, hs1, agg1);
    k_scatter1 <<<(N_EDGES + 3) / 4,     256, 0, stream>>>(src, dst, hs1, agg1);
    k_mm2      <<<(N_NODES + 7) / 8,     256, 0, stream>>>(agg1, W2, b1, dinv, hs2, agg2);
    k_scatter2 <<<(N_EDGES + 7) / 8,     256, 0, stream>>>(src, dst, hs2, agg2);
    k_pool     <<<(N_NODES + POOL_TILE - 1) / POOL_TILE, 256, 0, stream>>>(agg2, b2, dinv, batch, psum);
    k_final    <<<(N_GRAPHS * D_OUT + 255) / 256, 256, 0, stream>>>(psum, batch, out);
}

// Round 3
// 288.478 us; speedup vs baseline: 2.5037x; 1.4305x over previous
//
#include <hip/hip_runtime.h>

#define N_NODES 50000
#define N_EDGES 800000
#define N_GRAPHS 64
#define D_IN 128
#define D_HID 64
#define D_OUT 32
#define POOL_TILE 512
#define NB_SCAN ((N_NODES + 255) / 256)   // 196

// ------------------------------------------------------------- histogram ----
__global__ __launch_bounds__(256) void k_hist(const int* __restrict__ dst,
                                              int* __restrict__ hist) {
    int e = blockIdx.x * 256 + threadIdx.x;
    if (e < N_EDGES) atomicAdd(&hist[dst[e]], 1);
}

// ------------------------------------------------- exclusive scan (3-phase) -
__global__ __launch_bounds__(256) void k_scan1(const int* __restrict__ hist,
                                               int* __restrict__ rowptr,
                                               int* __restrict__ bsum) {
    __shared__ int tmp[256];
    int i = blockIdx.x * 256 + threadIdx.x;
    int v = (i < N_NODES) ? hist[i] : 0;
    tmp[threadIdx.x] = v;
    __syncthreads();
    for (int off = 1; off < 256; off <<= 1) {
        int t = (threadIdx.x >= off) ? tmp[threadIdx.x - off] : 0;
        __syncthreads();
        tmp[threadIdx.x] += t;
        __syncthreads();
    }
    if (i < N_NODES) rowptr[i] = tmp[threadIdx.x] - v;   // exclusive
    if (threadIdx.x == 255) bsum[blockIdx.x] = tmp[255];
}

__global__ __launch_bounds__(256) void k_scan2(int* __restrict__ bsum) {
    __shared__ int tmp[256];
    int v = (threadIdx.x < NB_SCAN) ? bsum[threadIdx.x] : 0;
    tmp[threadIdx.x] = v;
    __syncthreads();
    for (int off = 1; off < 256; off <<= 1) {
        int t = (threadIdx.x >= off) ? tmp[threadIdx.x - off] : 0;
        __syncthreads();
        tmp[threadIdx.x] += t;
        __syncthreads();
    }
    if (threadIdx.x < NB_SCAN) bsum[threadIdx.x] = tmp[threadIdx.x] - v;
}

__global__ __launch_bounds__(256) void k_scan3(const int* __restrict__ hist,
                                               int* __restrict__ rowptr,
                                               const int* __restrict__ bsum,
                                               int* __restrict__ cursor,
                                               float* __restrict__ dinv) {
    int i = blockIdx.x * 256 + threadIdx.x;
    if (i < N_NODES) {
        int r = rowptr[i] + bsum[blockIdx.x];
        rowptr[i] = r;
        cursor[i] = r;
        dinv[i] = rsqrtf((float)(hist[i] + 1));   // +1 self-loop
    }
    if (i == 0) rowptr[N_NODES] = N_EDGES;
}

// ------------------------------------------------------------- CSR fill -----
__global__ __launch_bounds__(256) void k_fill(const int* __restrict__ src,
                                              const int* __restrict__ dst,
                                              int* __restrict__ cursor,
                                              int* __restrict__ csr_src) {
    int e = blockIdx.x * 256 + threadIdx.x;
    if (e < N_EDGES) {
        int d = dst[e];
        int pos = atomicAdd(&cursor[d], 1);
        csr_src[pos] = src[e];
    }
}

// ------------------------------------------------- conv1 matmul (fused) -----
// hs1[u] = ((x[u]/max(rowsum,1)) @ W1) * dinv[u]
__global__ __launch_bounds__(256) void k_mm1(const float* __restrict__ x,
                                             const float* __restrict__ W1,
                                             const float* __restrict__ dinv,
                                             float* __restrict__ hs1) {
    __shared__ float w1s[D_IN * D_HID];      // 32 KiB
    __shared__ float xr[4][D_IN + 4];
    __shared__ float sinv[4];
    const int tid = threadIdx.x;

    for (int i = tid; i < D_IN * D_HID; i += 256) w1s[i] = W1[i];

    const int base = blockIdx.x * 4;
    for (int i = tid; i < 4 * D_IN; i += 256) {
        int nd = i >> 7, k = i & 127;
        int node = base + nd;
        xr[nd][k] = (node < N_NODES) ? x[(size_t)node * D_IN + k] : 0.0f;
    }
    __syncthreads();

    const int nd = tid >> 6, lane = tid & 63;
    float p = xr[nd][lane] + xr[nd][lane + 64];
    for (int off = 32; off > 0; off >>= 1) p += __shfl_down(p, off, 64);
    if (lane == 0) sinv[nd] = 1.0f / fmaxf(p, 1.0f);
    __syncthreads();

    const int c = tid & 63;
    const int node = base + nd;
    if (node < N_NODES) {
        float acc = 0.0f;
        #pragma unroll 8
        for (int k = 0; k < D_IN; ++k) acc += xr[nd][k] * w1s[k * D_HID + c];
        hs1[(size_t)node * D_HID + c] = acc * sinv[nd] * dinv[node];
    }
}

// -------------------------------------------------------------- gather1 -----
// one wave per node, lane = channel; CSR gather, plain store
__global__ __launch_bounds__(256) void k_gather1(const int* __restrict__ rowptr,
                                                 const int* __restrict__ csr_src,
                                                 const float* __restrict__ hs1,
                                                 float* __restrict__ agg1) {
    int v = blockIdx.x * 4 + (threadIdx.x >> 6);
    int lane = threadIdx.x & 63;
    if (v >= N_NODES) return;
    int beg = rowptr[v], end = rowptr[v + 1];
    float acc = hs1[(size_t)v * D_HID + lane];   // self-loop
    for (int base = beg; base < end; base += 64) {
        int n = min(64, end - base);
        int sidx = (lane < n) ? csr_src[base + lane] : 0;
        for (int j = 0; j < n; ++j) {
            int s = __shfl(sidx, j, 64);
            acc += hs1[(size_t)s * D_HID + lane];
        }
    }
    agg1[(size_t)v * D_HID + lane] = acc;
}

// ------------------------------- conv1 epilogue + conv2 matmul (fused) ------
__global__ __launch_bounds__(256) void k_mm2(const float* __restrict__ agg1,
                                             const float* __restrict__ W2,
                                             const float* __restrict__ b1,
                                             const float* __restrict__ dinv,
                                             float* __restrict__ hs2) {
    __shared__ float w2s[D_HID * D_OUT];     // 8 KiB
    __shared__ float h1s[8][D_HID];
    const int tid = threadIdx.x;

    for (int i = tid; i < D_HID * D_OUT; i += 256) w2s[i] = W2[i];

    const int base = blockIdx.x * 8;
    for (int i = tid; i < 8 * D_HID; i += 256) {
        int nd = i >> 6, k = i & 63;
        int node = base + nd;
        h1s[nd][k] = (node < N_NODES)
                   ? fmaxf(dinv[node] * agg1[(size_t)node * D_HID + k] + b1[k], 0.0f)
                   : 0.0f;
    }
    __syncthreads();

    const int nd = tid >> 5, c = tid & 31;
    const int node = base + nd;
    if (node < N_NODES) {
        float acc = 0.0f;
        #pragma unroll 8
        for (int k = 0; k < D_HID; ++k) acc += h1s[nd][k] * w2s[k * D_OUT + c];
        hs2[(size_t)node * D_OUT + c] = acc * dinv[node];
    }
}

// -------------------------------------------------------------- gather2 -----
// half-wave (32 lanes = channels) per node
__global__ __launch_bounds__(256) void k_gather2(const int* __restrict__ rowptr,
                                                 const int* __restrict__ csr_src,
                                                 const float* __restrict__ hs2,
                                                 float* __restrict__ agg2) {
    int v = blockIdx.x * 8 + (threadIdx.x >> 5);
    int lane = threadIdx.x & 31;
    if (v >= N_NODES) return;
    int beg = rowptr[v], end = rowptr[v + 1];
    float acc = hs2[(size_t)v * D_OUT + lane];   // self-loop
    for (int base = beg; base < end; base += 32) {
        int n = min(32, end - base);
        int sidx = (lane < n) ? csr_src[base + lane] : 0;
        for (int j = 0; j < n; ++j) {
            int s = __shfl(sidx, j, 32);
            acc += hs2[(size_t)s * D_OUT + lane];
        }
    }
    agg2[(size_t)v * D_OUT + lane] = acc;
}

// ------------------------------------------- conv2 epilogue + mean pool -----
__global__ __launch_bounds__(256) void k_pool(const float* __restrict__ agg2,
                                              const float* __restrict__ b2,
                                              const float* __restrict__ dinv,
                                              const int* __restrict__ batch,
                                              float* __restrict__ psum) {
    const int c = threadIdx.x & 31;
    const int slot = threadIdx.x >> 5;
    const int base = blockIdx.x * POOL_TILE;
    const float bc = b2[c];

    float acc = 0.0f;
    int curg = -1;
    for (int j = slot; j < POOL_TILE; j += 8) {
        int node = base + j;
        if (node >= N_NODES) break;
        float hv = fmaxf(dinv[node] * agg2[(size_t)node * D_OUT + c] + bc, 0.0f);
        int g = batch[node];
        if (g != curg) {
            if (curg >= 0) atomicAdd(&psum[curg * D_OUT + c], acc);
            curg = g;
            acc = 0.0f;
        }
        acc += hv;
    }
    if (curg >= 0) atomicAdd(&psum[curg * D_OUT + c], acc);
}

__global__ __launch_bounds__(256) void k_final(const float* __restrict__ psum,
                                               const int* __restrict__ batch,
                                               float* __restrict__ out) {
    int i = blockIdx.x * 256 + threadIdx.x;
    if (i < N_GRAPHS * D_OUT) {
        int g = i >> 5;   // D_OUT == 32
        int lo = 0, hi = N_NODES;
        while (lo < hi) { int m = (lo + hi) >> 1; if (batch[m] < g) lo = m + 1; else hi = m; }
        int lb = lo;
        lo = 0; hi = N_NODES;
        while (lo < hi) { int m = (lo + hi) >> 1; if (batch[m] <= g) lo = m + 1; else hi = m; }
        float cnt = (float)(lo - lb);
        out[i] = psum[i] / fmaxf(cnt, 1.0f);
    }
}

// ---------------------------------------------------------------------------
extern "C" void kernel_launch(void* const* d_in, const int* in_sizes, int n_in,
                              void* d_out, int out_size, void* d_ws, size_t ws_size,
                              hipStream_t stream) {
    const float* x     = (const float*)d_in[0];
    const int*   edge  = (const int*)d_in[1];   // [2, E]
    const int*   batch = (const int*)d_in[2];   // [N] sorted
    const float* W1    = (const float*)d_in[3];
    const float* b1    = (const float*)d_in[4];
    const float* W2    = (const float*)d_in[5];
    const float* b2    = (const float*)d_in[6];
    float* out = (float*)d_out;

    const int* src = edge;
    const int* dst = edge + N_EDGES;

    float* ws   = (float*)d_ws;
    float* dinv = ws;                                   // N
    float* hs1  = dinv + N_NODES;                       // N*64
    float* agg1 = hs1  + (size_t)N_NODES * D_HID;       // N*64
    float* hs2  = agg1 + (size_t)N_NODES * D_HID;       // N*32
    float* agg2 = hs2  + (size_t)N_NODES * D_OUT;       // N*32
    float* psum = agg2 + (size_t)N_NODES * D_OUT;       // G*32
    int* hist    = (int*)(psum + N_GRAPHS * D_OUT);     // N
    int* rowptr  = hist + N_NODES;                      // N+1
    int* cursor  = rowptr + N_NODES + 1;                // N
    int* bsum    = cursor + N_NODES;                    // NB_SCAN (<256)
    int* csr_src = bsum + 256;                          // E

    hipMemsetAsync(psum, 0, N_GRAPHS * D_OUT * sizeof(float), stream);
    hipMemsetAsync(hist, 0, N_NODES * sizeof(int), stream);

    k_hist   <<<(N_EDGES + 255) / 256, 256, 0, stream>>>(dst, hist);
    k_scan1  <<<NB_SCAN, 256, 0, stream>>>(hist, rowptr, bsum);
    k_scan2  <<<1, 256, 0, stream>>>(bsum);
    k_scan3  <<<NB_SCAN, 256, 0, stream>>>(hist, rowptr, bsum, cursor, dinv);
    k_fill   <<<(N_EDGES + 255) / 256, 256, 0, stream>>>(src, dst, cursor, csr_src);
    k_mm1    <<<(N_NODES + 3) / 4, 256, 0, stream>>>(x, W1, dinv, hs1);
    k_gather1<<<(N_NODES + 3) / 4, 256, 0, stream>>>(rowptr, csr_src, hs1, agg1);
    k_mm2    <<<(N_NODES + 7) / 8, 256, 0, stream>>>(agg1, W2, b1, dinv, hs2);
    k_gather2<<<(N_NODES + 7) / 8, 256, 0, stream>>>(rowptr, csr_src, hs2, agg2);
    k_pool   <<<(N_NODES + POOL_TILE - 1) / POOL_TILE, 256, 0, stream>>>(agg2, b2, dinv, batch, psum);
    k_final  <<<(N_GRAPHS * D_OUT + 255) / 256, 256, 0, stream>>>(psum, batch, out);
}